// Round 5
// baseline (1644.872 us; speedup 1.0000x reference)
//
#include <hip/hip_runtime.h>
#include <hip/hip_bf16.h>
#include <cstdint>
#include <cstddef>

typedef __bf16 bf16x8 __attribute__((ext_vector_type(8)));
typedef __bf16 bf16x4 __attribute__((ext_vector_type(4)));
typedef float floatx4 __attribute__((ext_vector_type(4)));

#define MFMA16(a, b, c) __builtin_amdgcn_mfma_f32_16x16x32_bf16((a), (b), (c), 0, 0, 0)

__device__ __forceinline__ void load_lds16(const __bf16* g, __bf16* l) {
  __builtin_amdgcn_global_load_lds(
      (const __attribute__((address_space(1))) uint32_t*)(g),
      (__attribute__((address_space(3))) uint32_t*)(l), 16, 0, 0);
}

// lgkm-only barrier: does NOT drain vmcnt, so global_load_lds DMA issued at
// the tile top stays in flight across it (T3/T4 pattern).
#define BAR_LGKM()                                        \
  do {                                                    \
    asm volatile("s_waitcnt lgkmcnt(0)" ::: "memory");    \
    __builtin_amdgcn_s_barrier();                         \
    __builtin_amdgcn_sched_barrier(0);                    \
  } while (0)

// m204 bijective XCD chunk swizzle: contiguous chunk of the grid per XCD
// (assumes dispatch round-robins blockIdx%8 across the 8 XCDs).
__device__ __forceinline__ int xcd_swizzle(int orig, int nwg) {
  int q = nwg >> 3, r = nwg & 7;
  int xcd = orig & 7, local = orig >> 3;
  return (xcd < r) ? xcd * (q + 1) + local : r * (q + 1) + (xcd - r) * q + local;
}

// ---------------------------------------------------------------------------
// LDS-tiled transpose: Wt[h*512+e][d] = W[h][d][e] * scale  (fp32 -> bf16)
// ---------------------------------------------------------------------------
__global__ __launch_bounds__(256) void tw_t(const float* __restrict__ W,
                                            __bf16* __restrict__ Wt, float scale) {
  __shared__ float tile[64][65];
  int h = blockIdx.z, d0 = blockIdx.y * 64, e0 = blockIdx.x * 64;
  int tx = threadIdx.x & 15, ty = threadIdx.x >> 4;
  const float* src = W + ((size_t)h * 512 + d0) * 512 + e0;
#pragma unroll
  for (int j = 0; j < 4; ++j) {
    int dd = ty + j * 16;
    float4 f = *(const float4*)&src[(size_t)dd * 512 + tx * 4];
    tile[dd][tx * 4 + 0] = f.x; tile[dd][tx * 4 + 1] = f.y;
    tile[dd][tx * 4 + 2] = f.z; tile[dd][tx * 4 + 3] = f.w;
  }
  __syncthreads();
  __bf16* dst = Wt + ((size_t)h * 512 + e0) * 512 + d0;
#pragma unroll
  for (int j = 0; j < 4; ++j) {
    int ee = ty + j * 16;
    bf16x4 v;
#pragma unroll
    for (int x = 0; x < 4; ++x) v[x] = (__bf16)(tile[tx * 4 + x][ee] * scale);
    *(bf16x4*)&dst[(size_t)ee * 512 + tx * 4] = v;
  }
}

// ---------------------------------------------------------------------------
// Wot[e][h*512+d] = Wo[d*8+h][e]   (LDS-tiled), grid (8,8,8)
// ---------------------------------------------------------------------------
__global__ __launch_bounds__(256) void wo_t(const float* __restrict__ Wo,
                                            __bf16* __restrict__ Wot) {
  __shared__ float tile[64][65];
  int h = blockIdx.z, d0 = blockIdx.y * 64, e0 = blockIdx.x * 64;
  int tx = threadIdx.x & 15, ty = threadIdx.x >> 4;
#pragma unroll
  for (int j = 0; j < 4; ++j) {
    int dd = ty + j * 16;
    float4 f = *(const float4*)&Wo[(size_t)((d0 + dd) * 8 + h) * 512 + e0 + tx * 4];
    tile[dd][tx * 4 + 0] = f.x; tile[dd][tx * 4 + 1] = f.y;
    tile[dd][tx * 4 + 2] = f.z; tile[dd][tx * 4 + 3] = f.w;
  }
  __syncthreads();
#pragma unroll
  for (int j = 0; j < 4; ++j) {
    int ee = ty + j * 16;
    bf16x4 v;
#pragma unroll
    for (int x = 0; x < 4; ++x) v[x] = (__bf16)tile[tx * 4 + x][ee];
    *(bf16x4*)&Wot[(size_t)(e0 + ee) * 4096 + h * 512 + d0 + tx * 4] = v;
  }
}

// ---------------------------------------------------------------------------
// fp32 -> bf16 bulk convert (RNE cast identical to gemm's former in-kernel
// cast -> downstream bit-identical)
// ---------------------------------------------------------------------------
__global__ __launch_bounds__(256) void cvt_bf16(const float* __restrict__ in,
                                                __bf16* __restrict__ out, int n8) {
  int i = blockIdx.x * 256 + threadIdx.x;
  if (i < n8) {
    float4 f0 = *(const float4*)&in[(size_t)i * 8];
    float4 f1 = *(const float4*)&in[(size_t)i * 8 + 4];
    bf16x8 v;
    v[0] = (__bf16)f0.x; v[1] = (__bf16)f0.y; v[2] = (__bf16)f0.z; v[3] = (__bf16)f0.w;
    v[4] = (__bf16)f1.x; v[5] = (__bf16)f1.y; v[6] = (__bf16)f1.z; v[7] = (__bf16)f1.w;
    *(bf16x8*)&out[(size_t)i * 8] = v;
  }
}

// ---------------------------------------------------------------------------
// GEMM: C = A[M,K] * Bt[N,K]^T (+ bias[col]*bscale). 128x128 tile, BK=64.
// R5: staging via global_load_lds (16B DMA) into LINEAR [128][64] LDS
// (m97 pattern; m151: +35% vs reg-staging at 128^2). Read-side bank
// conflicts are accepted -- T2 is null in the 2-phase regime (critical
// path is stage+barrier, m230/m233).
// ---------------------------------------------------------------------------
template <int EPI>
__global__ __launch_bounds__(256) void gemm_bt(const __bf16* __restrict__ A,
                                               const __bf16* __restrict__ Bt,
                                               const float* __restrict__ bias,
                                               void* __restrict__ Cout,
                                               int N, int K, float bscale) {
  __shared__ __align__(16) __bf16 sA[128 * 64];
  __shared__ __align__(16) __bf16 sB[128 * 64];
  const int tid = threadIdx.x;
  const int lane = tid & 63;
  const int wave = tid >> 6;
  const int lr = lane & 15;
  const int lq = lane >> 4;
  const int wm = (wave >> 1) * 64;
  const int wn = (wave & 1) * 64;
  const int bx = blockIdx.x, by = blockIdx.y;

  const floatx4 z4 = {0.f, 0.f, 0.f, 0.f};
  floatx4 acc[4][4];
#pragma unroll
  for (int i = 0; i < 4; ++i)
#pragma unroll
    for (int j = 0; j < 4; ++j) acc[i][j] = z4;

  const size_t abase = (size_t)(by * 128) * K;
  const size_t bbase = (size_t)(bx * 128) * K;
  const int col8 = (tid & 7) << 3;  // staging col offset (elems)

  for (int k0 = 0; k0 < K; k0 += 64) {
    // DMA staging: q = p*256+tid covers (row=q>>3, 8 cols at (q&7)*8);
    // LDS dest wave-uniform base + lane*16 (lane-linear, m104 rule).
#pragma unroll
    for (int p = 0; p < 4; ++p) {
      int row = (p * 256 + tid) >> 3;
      load_lds16(&A[abase + (size_t)row * K + k0 + col8], &sA[p * 2048 + wave * 512]);
      load_lds16(&Bt[bbase + (size_t)row * K + k0 + col8], &sB[p * 2048 + wave * 512]);
    }
    __syncthreads();  // drains DMA vmcnt
#pragma unroll
    for (int ks = 0; ks < 2; ++ks) {
      bf16x8 af[4], bfr[4];
#pragma unroll
      for (int mt = 0; mt < 4; ++mt)
        af[mt] = *(const bf16x8*)&sA[(wm + mt * 16 + lr) * 64 + ks * 32 + lq * 8];
#pragma unroll
      for (int nt = 0; nt < 4; ++nt)
        bfr[nt] = *(const bf16x8*)&sB[(wn + nt * 16 + lr) * 64 + ks * 32 + lq * 8];
#pragma unroll
      for (int mt = 0; mt < 4; ++mt)
#pragma unroll
        for (int nt = 0; nt < 4; ++nt) acc[mt][nt] = MFMA16(af[mt], bfr[nt], acc[mt][nt]);
    }
    __syncthreads();
  }

#pragma unroll
  for (int mt = 0; mt < 4; ++mt) {
#pragma unroll
    for (int nt = 0; nt < 4; ++nt) {
      int col = bx * 128 + wn + nt * 16 + lr;
      int row0 = by * 128 + wm + mt * 16 + lq * 4;
      float bcol = bias[col] * bscale;
      if (EPI == 0) {
        __bf16* dst = (__bf16*)Cout;
        int h = col >> 9, e = col & 511;
#pragma unroll
        for (int r = 0; r < 4; ++r) {
          int row = row0 + r;
          int b = row >> 11, m = row & 2047;
          dst[((size_t)((b << 3) | h) * 2048 + m) * 512 + e] = (__bf16)(acc[mt][nt][r] + bcol);
        }
      } else if (EPI == 1) {
        __bf16* dst = (__bf16*)Cout;
        int h = col >> 9, e = col & 511;
        int b = row0 >> 11, n = row0 & 2047;
        bf16x4 pk;
#pragma unroll
        for (int r = 0; r < 4; ++r) pk[r] = (__bf16)(acc[mt][nt][r] + bcol);
        *(bf16x4*)&dst[((size_t)((b << 3) | h) * 512 + e) * 2048 + n] = pk;
      } else {
        float* dst = (float*)Cout;
#pragma unroll
        for (int r = 0; r < 4; ++r) {
          int row = row0 + r;
          dst[(size_t)row * N + col] = acc[mt][nt][r] + bcol;
        }
      }
    }
  }
}

// ---------------------------------------------------------------------------
// Flash attention, LDS-staged, d-SPLIT QK + e-SLICED PV.
// R5 adds: (a) m204 bijective XCD chunk swizzle so all 16 mblk-blocks of a
// bh are co-located on one XCD (K/V tiles fetched once per XCD L2, not 8x);
// (b) T5 s_setprio(1) around the QK and PV MFMA clusters (3-phase structure
// has wave role diversity -> scheduler arbitration pays, m191).
// Structure unchanged from R4 (verified): kv-tile T=32, K/V dbuf via
// global_load_lds w/ XOR chunk swizzle on the global side; staging issued at
// tile top, drained only at B3; B1/B2 are lgkm-only barriers.
// ---------------------------------------------------------------------------
__global__ __launch_bounds__(512, 2) void attn_kernel(const __bf16* __restrict__ Qp,
                                                      const __bf16* __restrict__ Kp,
                                                      const __bf16* __restrict__ Vt,
                                                      __bf16* __restrict__ Outs) {
  __shared__ __align__(16) __bf16 kls[2][32 * 512];   // 64 KB
  __shared__ __align__(16) __bf16 vls[2][512 * 32];   // 64 KB
  __shared__ __align__(16) __bf16 pls[128 * 40];      // 10 KB, single buffer
  __shared__ __align__(16) floatx4 sx[2][8][64];      // 16 KB, single buffer
  __shared__ __align__(16) float l_red[128];          // row-sum exchange
  const int tid = threadIdx.x;
  const int lane = tid & 63;
  const int wave = tid >> 6;  // 0..7
  const int lr = lane & 15;
  const int lq = lane >> 4;
  const int blk = xcd_swizzle(blockIdx.x, gridDim.x);
  const int bh = blk >> 4;    // chunk-local b*8+h
  const int mblk = blk & 15;
  const int rp = (wave & 3) * 2;   // rowgroup pair base
  const int dh = wave >> 2;        // d-half of this wave
  const int fg = rp + dh;          // rowgroup this wave finalizes
  const int e0 = wave * 64;        // PV e-slice of this wave
  const int mbase = mblk * 128;
  const __bf16* Qb = Qp + (size_t)bh * (2048 * 512);
  const __bf16* Kb = Kp + (size_t)bh * (2048 * 512);
  const __bf16* Vb = Vt + (size_t)bh * (512 * 2048);

  // per-thread staging source offsets (swizzle on global side, LDS lane-linear)
  int gK[4], gV[4];
#pragma unroll
  for (int i = 0; i < 4; ++i) {
    int q = i * 512 + tid;
    int rK = q >> 6;
    gK[i] = rK * 512 + ((q & 63) ^ (rK & 7)) * 8;
    int eV = q >> 2;
    gV[i] = eV * 2048 + ((q & 3) ^ (eV & 3)) * 8;
  }

  // Q fragments: qf[0] = MY rowgroup (fg), qf[1] = partner's rowgroup, both
  // restricted to this wave's d-half. All register indices compile-time.
  bf16x8 qf[2][8];
#pragma unroll
  for (int ks = 0; ks < 8; ++ks) {
    qf[0][ks] = *(const bf16x8*)&Qb[(size_t)(mbase + fg * 16 + lr) * 512 +
                                    dh * 256 + ks * 32 + lq * 8];
    qf[1][ks] = *(const bf16x8*)&Qb[(size_t)(mbase + (rp + (dh ^ 1)) * 16 + lr) * 512 +
                                    dh * 256 + ks * 32 + lq * 8];
  }

  const floatx4 z4 = {0.f, 0.f, 0.f, 0.f};
  floatx4 o[8][4];  // [m-tile of 128 rows][e-tile of 64-col slice]
#pragma unroll
  for (int mt = 0; mt < 8; ++mt)
#pragma unroll
    for (int et = 0; et < 4; ++et) o[mt][et] = z4;
  float lsum[4] = {0.f, 0.f, 0.f, 0.f};

  // prologue: stage tile 0 into buffer 0
#pragma unroll
  for (int i = 0; i < 4; ++i) {
    load_lds16(Kb + gK[i], &kls[0][i * 4096 + wave * 512]);
    load_lds16(Vb + gV[i], &vls[0][i * 4096 + wave * 512]);
  }
  __syncthreads();

  for (int t = 0; t < 64; ++t) {
    const int cur = t & 1;
    // ---- issue async staging of tile t+1 FIRST (in flight until B3)
    if (t < 63) {
      const __bf16* kg = Kb + (size_t)(t + 1) * (32 * 512);
      const __bf16* vg = Vb + (t + 1) * 32;
#pragma unroll
      for (int i = 0; i < 4; ++i) {
        load_lds16(kg + gK[i], &kls[cur ^ 1][i * 4096 + wave * 512]);
        load_lds16(vg + gV[i], &vls[cur ^ 1][i * 4096 + wave * 512]);
      }
    }
    // ---- QK partials over this wave's d-half (static reg names)
    floatx4 sm0 = z4, sm1 = z4, sp0 = z4, sp1 = z4;
    const __bf16* kc = kls[cur];
    __builtin_amdgcn_s_setprio(1);
#pragma unroll
    for (int ks = 0; ks < 8; ++ks) {
      int cidx = ((dh * 32 + ks * 4 + lq) ^ (lr & 7)) * 8;
      bf16x8 k0 = *(const bf16x8*)&kc[lr * 512 + cidx];
      bf16x8 k1 = *(const bf16x8*)&kc[(16 + lr) * 512 + cidx];
      sm0 = MFMA16(qf[0][ks], k0, sm0);
      sm1 = MFMA16(qf[0][ks], k1, sm1);
      sp0 = MFMA16(qf[1][ks], k0, sp0);
      sp1 = MFMA16(qf[1][ks], k1, sp1);
    }
    __builtin_amdgcn_s_setprio(0);
    // ---- publish partner-rowgroup partials
    sx[0][wave][lane] = sp0;
    sx[1][wave][lane] = sp1;
    BAR_LGKM();  // B1: sx visible; staging DMA still in flight
    // ---- finalize rowgroup fg: mine + partner's, exp, P-write
    {
      floatx4 q0 = sx[0][wave ^ 4][lane];
      floatx4 q1 = sx[1][wave ^ 4][lane];
#pragma unroll
      for (int r = 0; r < 4; ++r) {
        float p0 = __expf(sm0[r] + q0[r]);
        float p1 = __expf(sm1[r] + q1[r]);
        lsum[r] += p0 + p1;
        pls[(fg * 16 + lq * 4 + r) * 40 + lr] = (__bf16)p0;
        pls[(fg * 16 + lq * 4 + r) * 40 + 16 + lr] = (__bf16)p1;
      }
    }
    BAR_LGKM();  // B2: pls visible; staging DMA still in flight
    // ---- PV(t) on this wave's e-slice
    {
      const __bf16* vc = vls[cur];
      bf16x8 vf[4];
#pragma unroll
      for (int et = 0; et < 4; ++et) {
        int e = e0 + et * 16 + lr;
        vf[et] = *(const bf16x8*)&vc[e * 32 + ((lq ^ (e & 3)) * 8)];
      }
      __builtin_amdgcn_s_setprio(1);
#pragma unroll
      for (int mt = 0; mt < 8; ++mt) {
        bf16x8 pf = *(const bf16x8*)&pls[(mt * 16 + lr) * 40 + lq * 8];
#pragma unroll
        for (int et = 0; et < 4; ++et) o[mt][et] = MFMA16(pf, vf[et], o[mt][et]);
      }
      __builtin_amdgcn_s_setprio(0);
    }
    __syncthreads();  // B3: drains staging vmcnt; guards all buffer reuse
  }

  // row-sum reduce (across lr) and exchange via LDS (O rows span all waves)
#pragma unroll
  for (int r = 0; r < 4; ++r) {
    float s = lsum[r];
    s += __shfl_xor(s, 1);
    s += __shfl_xor(s, 2);
    s += __shfl_xor(s, 4);
    s += __shfl_xor(s, 8);
    lsum[r] = s;
  }
  if (lr == 0) {
#pragma unroll
    for (int r = 0; r < 4; ++r) l_red[fg * 16 + lq * 4 + r] = lsum[r];
  }
  __syncthreads();

  int b = bh >> 3, h = bh & 7;
#pragma unroll
  for (int mt = 0; mt < 8; ++mt) {
    float4 lv = *(const float4*)&l_red[mt * 16 + lq * 4];
    float invr[4] = {1.0f / lv.x, 1.0f / lv.y, 1.0f / lv.z, 1.0f / lv.w};
    size_t rowbase = ((size_t)b * 2048 + mbase + mt * 16 + lq * 4) * 4096 + h * 512 + e0;
#pragma unroll
    for (int et = 0; et < 4; ++et)
#pragma unroll
      for (int r = 0; r < 4; ++r)
        Outs[rowbase + (size_t)r * 4096 + et * 16 + lr] = (__bf16)(o[mt][et][r] * invr[r]);
  }
}

// ---------------------------------------------------------------------------
extern "C" void kernel_launch(void* const* d_in, const int* in_sizes, int n_in,
                              void* d_out, int out_size, void* d_ws, size_t ws_size,
                              hipStream_t stream) {
  (void)in_sizes; (void)n_in; (void)out_size;
  const float* kin = (const float*)d_in[0];
  const float* vin = (const float*)d_in[1];
  const float* qin = (const float*)d_in[2];
  const float* Wk  = (const float*)d_in[3];
  const float* bk  = (const float*)d_in[4];
  const float* Wv  = (const float*)d_in[5];
  const float* bv  = (const float*)d_in[6];
  const float* Wq  = (const float*)d_in[7];
  const float* bq  = (const float*)d_in[8];
  const float* Wo  = (const float*)d_in[9];
  const float* bo  = (const float*)d_in[10];
  float* out = (float*)d_out;
  char* ws = (char*)d_ws;

  const float scale = 0.044194173824159216f;  // 1/sqrt(512), folded into Wq/bq

  const size_t SZ_W = (size_t)4096 * 512 * 2;
  const size_t SZ_B = (size_t)8 * 2048 * 512 * 2;
  const size_t FIXED = 4 * SZ_W;

  int nb = 1;
  if (ws_size >= FIXED + 8 * 4 * SZ_B) nb = 8;
  else if (ws_size >= FIXED + 4 * 4 * SZ_B) nb = 4;
  else if (ws_size >= FIXED + 2 * 4 * SZ_B) nb = 2;

  __bf16* Wkt = (__bf16*)(ws);
  __bf16* Wvt = (__bf16*)(ws + SZ_W);
  __bf16* Wqt = (__bf16*)(ws + 2 * SZ_W);
  __bf16* Wot = (__bf16*)(ws + 3 * SZ_W);
  char* chunkbase = ws + FIXED;
  __bf16* kproj = (__bf16*)(chunkbase);
  __bf16* qproj = (__bf16*)(chunkbase + (size_t)nb * SZ_B);
  __bf16* vt    = (__bf16*)(chunkbase + (size_t)nb * 2 * SZ_B);
  __bf16* outs  = (__bf16*)(chunkbase + (size_t)nb * 3 * SZ_B);

  tw_t<<<dim3(8, 8, 8), dim3(256), 0, stream>>>(Wk, Wkt, 1.0f);
  tw_t<<<dim3(8, 8, 8), dim3(256), 0, stream>>>(Wv, Wvt, 1.0f);
  tw_t<<<dim3(8, 8, 8), dim3(256), 0, stream>>>(Wq, Wqt, scale);
  wo_t<<<dim3(8, 8, 8), dim3(256), 0, stream>>>(Wo, Wot);

  for (int b0 = 0; b0 < 8; b0 += nb) {
    const float* kc = kin + (size_t)b0 * 2048 * 512;
    const float* vc = vin + (size_t)b0 * 2048 * 512;
    const float* qc = qin + (size_t)b0 * 2048 * 512;
    // pre-convert chunk inputs to bf16 (bit-identical RNE cast) into the
    // currently-unused 'outs' region (consumed by proj GEMMs before attn
    // overwrites outs).
    const size_t chunk_els = (size_t)nb * 2048 * 512;
    __bf16* kb16 = outs;
    __bf16* qb16 = outs + chunk_els;
    __bf16* vb16 = outs + 2 * chunk_els;
    int n8 = (int)(chunk_els / 8);
    int cvgrid = (n8 + 255) / 256;
    cvt_bf16<<<dim3(cvgrid), dim3(256), 0, stream>>>(kc, kb16, n8);
    cvt_bf16<<<dim3(cvgrid), dim3(256), 0, stream>>>(qc, qb16, n8);
    cvt_bf16<<<dim3(cvgrid), dim3(256), 0, stream>>>(vc, vb16, n8);
    gemm_bt<0><<<dim3(32, nb * 16), dim3(256), 0, stream>>>(kb16, Wkt, bk, (void*)kproj, 4096, 512, 1.0f);
    gemm_bt<0><<<dim3(32, nb * 16), dim3(256), 0, stream>>>(qb16, Wqt, bq, (void*)qproj, 4096, 512, scale);
    gemm_bt<1><<<dim3(32, nb * 16), dim3(256), 0, stream>>>(vb16, Wvt, bv, (void*)vt, 4096, 512, 1.0f);
    attn_kernel<<<dim3(nb * 128), dim3(512), 0, stream>>>(qproj, kproj, vt, outs);
    gemm_bt<2><<<dim3(4, nb * 16), dim3(256), 0, stream>>>(
        outs, Wot, bo, (void*)(out + (size_t)b0 * 2048 * 512), 512, 4096, 1.0f);
  }
}

// Round 6
// 1525.743 us; speedup vs baseline: 1.0781x; 1.0781x over previous
//
#include <hip/hip_runtime.h>
#include <hip/hip_bf16.h>
#include <cstdint>
#include <cstddef>

typedef __bf16 bf16x8 __attribute__((ext_vector_type(8)));
typedef __bf16 bf16x4 __attribute__((ext_vector_type(4)));
typedef float floatx4 __attribute__((ext_vector_type(4)));

#define MFMA16(a, b, c) __builtin_amdgcn_mfma_f32_16x16x32_bf16((a), (b), (c), 0, 0, 0)

__device__ __forceinline__ void load_lds16(const __bf16* g, __bf16* l) {
  __builtin_amdgcn_global_load_lds(
      (const __attribute__((address_space(1))) uint32_t*)(g),
      (__attribute__((address_space(3))) uint32_t*)(l), 16, 0, 0);
}

// lgkm-only barrier: does NOT drain vmcnt, so global_load_lds DMA issued at
// the tile top stays in flight across it (T3/T4 pattern).
#define BAR_LGKM()                                        \
  do {                                                    \
    asm volatile("s_waitcnt lgkmcnt(0)" ::: "memory");    \
    __builtin_amdgcn_s_barrier();                         \
    __builtin_amdgcn_sched_barrier(0);                    \
  } while (0)

// m204 bijective XCD chunk swizzle: contiguous chunk of the grid per XCD.
// R5 verified its mechanism on this kernel: attn FETCH 280 MB -> 50 MB.
__device__ __forceinline__ int xcd_swizzle(int orig, int nwg) {
  int q = nwg >> 3, r = nwg & 7;
  int xcd = orig & 7, local = orig >> 3;
  return (xcd < r) ? xcd * (q + 1) + local : r * (q + 1) + (xcd - r) * q + local;
}

// ---------------------------------------------------------------------------
// LDS-tiled transpose: Wt[h*512+e][d] = W[h][d][e] * scale  (fp32 -> bf16)
// ---------------------------------------------------------------------------
__global__ __launch_bounds__(256) void tw_t(const float* __restrict__ W,
                                            __bf16* __restrict__ Wt, float scale) {
  __shared__ float tile[64][65];
  int h = blockIdx.z, d0 = blockIdx.y * 64, e0 = blockIdx.x * 64;
  int tx = threadIdx.x & 15, ty = threadIdx.x >> 4;
  const float* src = W + ((size_t)h * 512 + d0) * 512 + e0;
#pragma unroll
  for (int j = 0; j < 4; ++j) {
    int dd = ty + j * 16;
    float4 f = *(const float4*)&src[(size_t)dd * 512 + tx * 4];
    tile[dd][tx * 4 + 0] = f.x; tile[dd][tx * 4 + 1] = f.y;
    tile[dd][tx * 4 + 2] = f.z; tile[dd][tx * 4 + 3] = f.w;
  }
  __syncthreads();
  __bf16* dst = Wt + ((size_t)h * 512 + e0) * 512 + d0;
#pragma unroll
  for (int j = 0; j < 4; ++j) {
    int ee = ty + j * 16;
    bf16x4 v;
#pragma unroll
    for (int x = 0; x < 4; ++x) v[x] = (__bf16)(tile[tx * 4 + x][ee] * scale);
    *(bf16x4*)&dst[(size_t)ee * 512 + tx * 4] = v;
  }
}

// ---------------------------------------------------------------------------
// Wot[e][h*512+d] = Wo[d*8+h][e]   (LDS-tiled), grid (8,8,8)
// ---------------------------------------------------------------------------
__global__ __launch_bounds__(256) void wo_t(const float* __restrict__ Wo,
                                            __bf16* __restrict__ Wot) {
  __shared__ float tile[64][65];
  int h = blockIdx.z, d0 = blockIdx.y * 64, e0 = blockIdx.x * 64;
  int tx = threadIdx.x & 15, ty = threadIdx.x >> 4;
#pragma unroll
  for (int j = 0; j < 4; ++j) {
    int dd = ty + j * 16;
    float4 f = *(const float4*)&Wo[(size_t)((d0 + dd) * 8 + h) * 512 + e0 + tx * 4];
    tile[dd][tx * 4 + 0] = f.x; tile[dd][tx * 4 + 1] = f.y;
    tile[dd][tx * 4 + 2] = f.z; tile[dd][tx * 4 + 3] = f.w;
  }
  __syncthreads();
#pragma unroll
  for (int j = 0; j < 4; ++j) {
    int ee = ty + j * 16;
    bf16x4 v;
#pragma unroll
    for (int x = 0; x < 4; ++x) v[x] = (__bf16)tile[tx * 4 + x][ee];
    *(bf16x4*)&Wot[(size_t)(e0 + ee) * 4096 + h * 512 + d0 + tx * 4] = v;
  }
}

// ---------------------------------------------------------------------------
// fp32 -> bf16 bulk convert, 3 tensors in one launch (blockIdx.y selects).
// RNE cast identical to the GEMM's former in-kernel cast -> bit-identical.
// ---------------------------------------------------------------------------
__global__ __launch_bounds__(256) void cvt_bf16x3(const float* __restrict__ in0,
                                                  const float* __restrict__ in1,
                                                  const float* __restrict__ in2,
                                                  __bf16* __restrict__ out0,
                                                  __bf16* __restrict__ out1,
                                                  __bf16* __restrict__ out2,
                                                  int n8) {
  int i = blockIdx.x * 256 + threadIdx.x;
  if (i >= n8) return;
  const float* in = (blockIdx.y == 0) ? in0 : (blockIdx.y == 1) ? in1 : in2;
  __bf16* out = (blockIdx.y == 0) ? out0 : (blockIdx.y == 1) ? out1 : out2;
  float4 f0 = *(const float4*)&in[(size_t)i * 8];
  float4 f1 = *(const float4*)&in[(size_t)i * 8 + 4];
  bf16x8 v;
  v[0] = (__bf16)f0.x; v[1] = (__bf16)f0.y; v[2] = (__bf16)f0.z; v[3] = (__bf16)f0.w;
  v[4] = (__bf16)f1.x; v[5] = (__bf16)f1.y; v[6] = (__bf16)f1.z; v[7] = (__bf16)f1.w;
  *(bf16x8*)&out[(size_t)i * 8] = v;
}

// ---------------------------------------------------------------------------
// GEMM: C = A[M,K] * Bt[N,K]^T (+ bias[col]*bscale). 128x128 tile, BK=64.
// R6: reverted to R4's reg-staged + padded-LDS staging (R5's global_load_lds
// + linear LDS A/B'd WORSE here: short K=512 loop, 16-way read conflicts).
// ---------------------------------------------------------------------------
template <int EPI>
__global__ __launch_bounds__(256) void gemm_bt(const __bf16* __restrict__ A,
                                               const __bf16* __restrict__ Bt,
                                               const float* __restrict__ bias,
                                               void* __restrict__ Cout,
                                               int N, int K, float bscale) {
  __shared__ __align__(16) __bf16 sA[128][72];
  __shared__ __align__(16) __bf16 sB[128][72];
  const int tid = threadIdx.x;
  const int lane = tid & 63;
  const int wave = tid >> 6;
  const int lr = lane & 15;
  const int lq = lane >> 4;
  const int wm = (wave >> 1) * 64;
  const int wn = (wave & 1) * 64;
  const int bx = blockIdx.x, by = blockIdx.y;
  const int srow = tid >> 3;
  const int scol = (tid & 7) << 3;

  const floatx4 z4 = {0.f, 0.f, 0.f, 0.f};
  floatx4 acc[4][4];
#pragma unroll
  for (int i = 0; i < 4; ++i)
#pragma unroll
    for (int j = 0; j < 4; ++j) acc[i][j] = z4;

  const size_t abase = (size_t)(by * 128) * K;
  const size_t bbase = (size_t)(bx * 128) * K;

  for (int k0 = 0; k0 < K; k0 += 64) {
#pragma unroll
    for (int p = 0; p < 4; ++p) {
      int row = p * 32 + srow;
      *(bf16x8*)&sA[row][scol] = *(const bf16x8*)&A[abase + (size_t)row * K + k0 + scol];
      *(bf16x8*)&sB[row][scol] = *(const bf16x8*)&Bt[bbase + (size_t)row * K + k0 + scol];
    }
    __syncthreads();
#pragma unroll
    for (int ks = 0; ks < 2; ++ks) {
      bf16x8 af[4], bfr[4];
#pragma unroll
      for (int mt = 0; mt < 4; ++mt)
        af[mt] = *(const bf16x8*)&sA[wm + mt * 16 + lr][ks * 32 + lq * 8];
#pragma unroll
      for (int nt = 0; nt < 4; ++nt)
        bfr[nt] = *(const bf16x8*)&sB[wn + nt * 16 + lr][ks * 32 + lq * 8];
#pragma unroll
      for (int mt = 0; mt < 4; ++mt)
#pragma unroll
        for (int nt = 0; nt < 4; ++nt) acc[mt][nt] = MFMA16(af[mt], bfr[nt], acc[mt][nt]);
    }
    __syncthreads();
  }

#pragma unroll
  for (int mt = 0; mt < 4; ++mt) {
#pragma unroll
    for (int nt = 0; nt < 4; ++nt) {
      int col = bx * 128 + wn + nt * 16 + lr;
      int row0 = by * 128 + wm + mt * 16 + lq * 4;
      float bcol = bias[col] * bscale;
      if (EPI == 0) {
        __bf16* dst = (__bf16*)Cout;
        int h = col >> 9, e = col & 511;
#pragma unroll
        for (int r = 0; r < 4; ++r) {
          int row = row0 + r;
          int b = row >> 11, m = row & 2047;
          dst[((size_t)((b << 3) | h) * 2048 + m) * 512 + e] = (__bf16)(acc[mt][nt][r] + bcol);
        }
      } else if (EPI == 1) {
        __bf16* dst = (__bf16*)Cout;
        int h = col >> 9, e = col & 511;
        int b = row0 >> 11, n = row0 & 2047;
        bf16x4 pk;
#pragma unroll
        for (int r = 0; r < 4; ++r) pk[r] = (__bf16)(acc[mt][nt][r] + bcol);
        *(bf16x4*)&dst[((size_t)((b << 3) | h) * 512 + e) * 2048 + n] = pk;
      } else {
        float* dst = (float*)Cout;
#pragma unroll
        for (int r = 0; r < 4; ++r) {
          int row = row0 + r;
          dst[(size_t)row * N + col] = acc[mt][nt][r] + bcol;
        }
      }
    }
  }
}

// ---------------------------------------------------------------------------
// Flash attention, LDS-staged, d-SPLIT QK + e-SLICED PV.
// R6 = R4 structure exactly (verified 201 us), plus ONLY the XCD chunk
// swizzle (R5 verified FETCH 280->50 MB; isolating its time effect).
// setprio REVERTED (R5 suspect: lockstep 8-wave blocks = m190 regime).
// ---------------------------------------------------------------------------
__global__ __launch_bounds__(512, 2) void attn_kernel(const __bf16* __restrict__ Qp,
                                                      const __bf16* __restrict__ Kp,
                                                      const __bf16* __restrict__ Vt,
                                                      __bf16* __restrict__ Outs) {
  __shared__ __align__(16) __bf16 kls[2][32 * 512];   // 64 KB
  __shared__ __align__(16) __bf16 vls[2][512 * 32];   // 64 KB
  __shared__ __align__(16) __bf16 pls[128 * 40];      // 10 KB, single buffer
  __shared__ __align__(16) floatx4 sx[2][8][64];      // 16 KB, single buffer
  __shared__ __align__(16) float l_red[128];          // row-sum exchange
  const int tid = threadIdx.x;
  const int lane = tid & 63;
  const int wave = tid >> 6;  // 0..7
  const int lr = lane & 15;
  const int lq = lane >> 4;
  const int blk = xcd_swizzle(blockIdx.x, gridDim.x);
  const int bh = blk >> 4;    // chunk-local b*8+h
  const int mblk = blk & 15;
  const int rp = (wave & 3) * 2;   // rowgroup pair base
  const int dh = wave >> 2;        // d-half of this wave
  const int fg = rp + dh;          // rowgroup this wave finalizes
  const int e0 = wave * 64;        // PV e-slice of this wave
  const int mbase = mblk * 128;
  const __bf16* Qb = Qp + (size_t)bh * (2048 * 512);
  const __bf16* Kb = Kp + (size_t)bh * (2048 * 512);
  const __bf16* Vb = Vt + (size_t)bh * (512 * 2048);

  // per-thread staging source offsets (swizzle on global side, LDS lane-linear)
  int gK[4], gV[4];
#pragma unroll
  for (int i = 0; i < 4; ++i) {
    int q = i * 512 + tid;
    int rK = q >> 6;
    gK[i] = rK * 512 + ((q & 63) ^ (rK & 7)) * 8;
    int eV = q >> 2;
    gV[i] = eV * 2048 + ((q & 3) ^ (eV & 3)) * 8;
  }

  // Q fragments: qf[0] = MY rowgroup (fg), qf[1] = partner's rowgroup, both
  // restricted to this wave's d-half. All register indices compile-time.
  bf16x8 qf[2][8];
#pragma unroll
  for (int ks = 0; ks < 8; ++ks) {
    qf[0][ks] = *(const bf16x8*)&Qb[(size_t)(mbase + fg * 16 + lr) * 512 +
                                    dh * 256 + ks * 32 + lq * 8];
    qf[1][ks] = *(const bf16x8*)&Qb[(size_t)(mbase + (rp + (dh ^ 1)) * 16 + lr) * 512 +
                                    dh * 256 + ks * 32 + lq * 8];
  }

  const floatx4 z4 = {0.f, 0.f, 0.f, 0.f};
  floatx4 o[8][4];  // [m-tile of 128 rows][e-tile of 64-col slice]
#pragma unroll
  for (int mt = 0; mt < 8; ++mt)
#pragma unroll
    for (int et = 0; et < 4; ++et) o[mt][et] = z4;
  float lsum[4] = {0.f, 0.f, 0.f, 0.f};

  // prologue: stage tile 0 into buffer 0
#pragma unroll
  for (int i = 0; i < 4; ++i) {
    load_lds16(Kb + gK[i], &kls[0][i * 4096 + wave * 512]);
    load_lds16(Vb + gV[i], &vls[0][i * 4096 + wave * 512]);
  }
  __syncthreads();

  for (int t = 0; t < 64; ++t) {
    const int cur = t & 1;
    // ---- issue async staging of tile t+1 FIRST (in flight until B3)
    if (t < 63) {
      const __bf16* kg = Kb + (size_t)(t + 1) * (32 * 512);
      const __bf16* vg = Vb + (t + 1) * 32;
#pragma unroll
      for (int i = 0; i < 4; ++i) {
        load_lds16(kg + gK[i], &kls[cur ^ 1][i * 4096 + wave * 512]);
        load_lds16(vg + gV[i], &vls[cur ^ 1][i * 4096 + wave * 512]);
      }
    }
    // ---- QK partials over this wave's d-half (static reg names)
    floatx4 sm0 = z4, sm1 = z4, sp0 = z4, sp1 = z4;
    const __bf16* kc = kls[cur];
#pragma unroll
    for (int ks = 0; ks < 8; ++ks) {
      int cidx = ((dh * 32 + ks * 4 + lq) ^ (lr & 7)) * 8;
      bf16x8 k0 = *(const bf16x8*)&kc[lr * 512 + cidx];
      bf16x8 k1 = *(const bf16x8*)&kc[(16 + lr) * 512 + cidx];
      sm0 = MFMA16(qf[0][ks], k0, sm0);
      sm1 = MFMA16(qf[0][ks], k1, sm1);
      sp0 = MFMA16(qf[1][ks], k0, sp0);
      sp1 = MFMA16(qf[1][ks], k1, sp1);
    }
    // ---- publish partner-rowgroup partials
    sx[0][wave][lane] = sp0;
    sx[1][wave][lane] = sp1;
    BAR_LGKM();  // B1: sx visible; staging DMA still in flight
    // ---- finalize rowgroup fg: mine + partner's, exp, P-write
    {
      floatx4 q0 = sx[0][wave ^ 4][lane];
      floatx4 q1 = sx[1][wave ^ 4][lane];
#pragma unroll
      for (int r = 0; r < 4; ++r) {
        float p0 = __expf(sm0[r] + q0[r]);
        float p1 = __expf(sm1[r] + q1[r]);
        lsum[r] += p0 + p1;
        pls[(fg * 16 + lq * 4 + r) * 40 + lr] = (__bf16)p0;
        pls[(fg * 16 + lq * 4 + r) * 40 + 16 + lr] = (__bf16)p1;
      }
    }
    BAR_LGKM();  // B2: pls visible; staging DMA still in flight
    // ---- PV(t) on this wave's e-slice
    {
      const __bf16* vc = vls[cur];
      bf16x8 vf[4];
#pragma unroll
      for (int et = 0; et < 4; ++et) {
        int e = e0 + et * 16 + lr;
        vf[et] = *(const bf16x8*)&vc[e * 32 + ((lq ^ (e & 3)) * 8)];
      }
#pragma unroll
      for (int mt = 0; mt < 8; ++mt) {
        bf16x8 pf = *(const bf16x8*)&pls[(mt * 16 + lr) * 40 + lq * 8];
#pragma unroll
        for (int et = 0; et < 4; ++et) o[mt][et] = MFMA16(pf, vf[et], o[mt][et]);
      }
    }
    __syncthreads();  // B3: drains staging vmcnt; guards all buffer reuse
  }

  // row-sum reduce (across lr) and exchange via LDS (O rows span all waves)
#pragma unroll
  for (int r = 0; r < 4; ++r) {
    float s = lsum[r];
    s += __shfl_xor(s, 1);
    s += __shfl_xor(s, 2);
    s += __shfl_xor(s, 4);
    s += __shfl_xor(s, 8);
    lsum[r] = s;
  }
  if (lr == 0) {
#pragma unroll
    for (int r = 0; r < 4; ++r) l_red[fg * 16 + lq * 4 + r] = lsum[r];
  }
  __syncthreads();

  int b = bh >> 3, h = bh & 7;
#pragma unroll
  for (int mt = 0; mt < 8; ++mt) {
    float4 lv = *(const float4*)&l_red[mt * 16 + lq * 4];
    float invr[4] = {1.0f / lv.x, 1.0f / lv.y, 1.0f / lv.z, 1.0f / lv.w};
    size_t rowbase = ((size_t)b * 2048 + mbase + mt * 16 + lq * 4) * 4096 + h * 512 + e0;
#pragma unroll
    for (int et = 0; et < 4; ++et)
#pragma unroll
      for (int r = 0; r < 4; ++r)
        Outs[rowbase + (size_t)r * 4096 + et * 16 + lr] = (__bf16)(o[mt][et][r] * invr[r]);
  }
}

// ---------------------------------------------------------------------------
extern "C" void kernel_launch(void* const* d_in, const int* in_sizes, int n_in,
                              void* d_out, int out_size, void* d_ws, size_t ws_size,
                              hipStream_t stream) {
  (void)in_sizes; (void)n_in; (void)out_size;
  const float* kin = (const float*)d_in[0];
  const float* vin = (const float*)d_in[1];
  const float* qin = (const float*)d_in[2];
  const float* Wk  = (const float*)d_in[3];
  const float* bk  = (const float*)d_in[4];
  const float* Wv  = (const float*)d_in[5];
  const float* bv  = (const float*)d_in[6];
  const float* Wq  = (const float*)d_in[7];
  const float* bq  = (const float*)d_in[8];
  const float* Wo  = (const float*)d_in[9];
  const float* bo  = (const float*)d_in[10];
  float* out = (float*)d_out;
  char* ws = (char*)d_ws;

  const float scale = 0.044194173824159216f;  // 1/sqrt(512), folded into Wq/bq

  const size_t SZ_W = (size_t)4096 * 512 * 2;
  const size_t SZ_B = (size_t)8 * 2048 * 512 * 2;
  const size_t FIXED = 4 * SZ_W;

  int nb = 1;
  if (ws_size >= FIXED + 8 * 4 * SZ_B) nb = 8;
  else if (ws_size >= FIXED + 4 * 4 * SZ_B) nb = 4;
  else if (ws_size >= FIXED + 2 * 4 * SZ_B) nb = 2;

  __bf16* Wkt = (__bf16*)(ws);
  __bf16* Wvt = (__bf16*)(ws + SZ_W);
  __bf16* Wqt = (__bf16*)(ws + 2 * SZ_W);
  __bf16* Wot = (__bf16*)(ws + 3 * SZ_W);
  char* chunkbase = ws + FIXED;
  __bf16* kproj = (__bf16*)(chunkbase);
  __bf16* qproj = (__bf16*)(chunkbase + (size_t)nb * SZ_B);
  __bf16* vt    = (__bf16*)(chunkbase + (size_t)nb * 2 * SZ_B);
  __bf16* outs  = (__bf16*)(chunkbase + (size_t)nb * 3 * SZ_B);

  tw_t<<<dim3(8, 8, 8), dim3(256), 0, stream>>>(Wk, Wkt, 1.0f);
  tw_t<<<dim3(8, 8, 8), dim3(256), 0, stream>>>(Wv, Wvt, 1.0f);
  tw_t<<<dim3(8, 8, 8), dim3(256), 0, stream>>>(Wq, Wqt, scale);
  wo_t<<<dim3(8, 8, 8), dim3(256), 0, stream>>>(Wo, Wot);

  for (int b0 = 0; b0 < 8; b0 += nb) {
    const float* kc = kin + (size_t)b0 * 2048 * 512;
    const float* vc = vin + (size_t)b0 * 2048 * 512;
    const float* qc = qin + (size_t)b0 * 2048 * 512;
    // pre-convert chunk inputs to bf16 (bit-identical RNE cast) into the
    // currently-unused 'outs' region (consumed by proj GEMMs before attn
    // overwrites outs). One fused launch for k,q,v.
    const size_t chunk_els = (size_t)nb * 2048 * 512;
    __bf16* kb16 = outs;
    __bf16* qb16 = outs + chunk_els;
    __bf16* vb16 = outs + 2 * chunk_els;
    int n8 = (int)(chunk_els / 8);
    int cvgrid = (n8 + 255) / 256;
    cvt_bf16x3<<<dim3(cvgrid, 3), dim3(256), 0, stream>>>(kc, qc, vc, kb16, qb16, vb16, n8);
    gemm_bt<0><<<dim3(32, nb * 16), dim3(256), 0, stream>>>(kb16, Wkt, bk, (void*)kproj, 4096, 512, 1.0f);
    gemm_bt<0><<<dim3(32, nb * 16), dim3(256), 0, stream>>>(qb16, Wqt, bq, (void*)qproj, 4096, 512, scale);
    gemm_bt<1><<<dim3(32, nb * 16), dim3(256), 0, stream>>>(vb16, Wvt, bv, (void*)vt, 4096, 512, 1.0f);
    attn_kernel<<<dim3(nb * 128), dim3(512), 0, stream>>>(qproj, kproj, vt, outs);
    gemm_bt<2><<<dim3(4, nb * 16), dim3(256), 0, stream>>>(
        outs, Wot, bo, (void*)(out + (size_t)b0 * 2048 * 512), 512, 4096, 1.0f);
  }
}

// Round 7
// 1422.063 us; speedup vs baseline: 1.1567x; 1.0729x over previous
//
#include <hip/hip_runtime.h>
#include <hip/hip_bf16.h>
#include <cstdint>
#include <cstddef>

typedef __bf16 bf16x8 __attribute__((ext_vector_type(8)));
typedef __bf16 bf16x4 __attribute__((ext_vector_type(4)));
typedef float floatx4 __attribute__((ext_vector_type(4)));

#define MFMA16(a, b, c) __builtin_amdgcn_mfma_f32_16x16x32_bf16((a), (b), (c), 0, 0, 0)

__device__ __forceinline__ void load_lds16(const __bf16* g, __bf16* l) {
  __builtin_amdgcn_global_load_lds(
      (const __attribute__((address_space(1))) uint32_t*)(g),
      (__attribute__((address_space(3))) uint32_t*)(l), 16, 0, 0);
}

// lgkm-only barrier: does NOT drain vmcnt, so global_load_lds DMA issued at
// the tile top stays in flight across it (T3/T4 pattern).
#define BAR_LGKM()                                        \
  do {                                                    \
    asm volatile("s_waitcnt lgkmcnt(0)" ::: "memory");    \
    __builtin_amdgcn_s_barrier();                         \
    __builtin_amdgcn_sched_barrier(0);                    \
  } while (0)

// m204 bijective XCD chunk swizzle: contiguous chunk of the grid per XCD.
// Verified on this kernel (R5/R6): attn FETCH 280 MB -> 50 MB. Kept because
// it makes K/V L2-resident per XCD -- prerequisite for V direct-load below.
__device__ __forceinline__ int xcd_swizzle(int orig, int nwg) {
  int q = nwg >> 3, r = nwg & 7;
  int xcd = orig & 7, local = orig >> 3;
  return (xcd < r) ? xcd * (q + 1) + local : r * (q + 1) + (xcd - r) * q + local;
}

// ---------------------------------------------------------------------------
// All four weight transposes in ONE launch. grid (8,8,32):
//   z>>3 = which (0:Wk, 1:Wv, 2:Wq w/ scale, 3:Wo), z&7 = h.
// which<3: Wt[h*512+e][d] = W[h][d][e] * s     (fp32 -> bf16)
// which=3: Wot[e][h*512+d] = Wo[d*8+h][e]
// ---------------------------------------------------------------------------
__global__ __launch_bounds__(256) void wt_all(const float* __restrict__ Wk,
                                              const float* __restrict__ Wv,
                                              const float* __restrict__ Wq,
                                              const float* __restrict__ Wo,
                                              __bf16* __restrict__ Wkt,
                                              __bf16* __restrict__ Wvt,
                                              __bf16* __restrict__ Wqt,
                                              __bf16* __restrict__ Wot,
                                              float qscale) {
  __shared__ float tile[64][65];
  int z = blockIdx.z;
  int which = z >> 3, h = z & 7;
  int d0 = blockIdx.y * 64, e0 = blockIdx.x * 64;
  int tx = threadIdx.x & 15, ty = threadIdx.x >> 4;
  if (which < 3) {
    const float* W = (which == 0) ? Wk : (which == 1) ? Wv : Wq;
    __bf16* Wt = (which == 0) ? Wkt : (which == 1) ? Wvt : Wqt;
    float scale = (which == 2) ? qscale : 1.0f;
    const float* src = W + ((size_t)h * 512 + d0) * 512 + e0;
#pragma unroll
    for (int j = 0; j < 4; ++j) {
      int dd = ty + j * 16;
      float4 f = *(const float4*)&src[(size_t)dd * 512 + tx * 4];
      tile[dd][tx * 4 + 0] = f.x; tile[dd][tx * 4 + 1] = f.y;
      tile[dd][tx * 4 + 2] = f.z; tile[dd][tx * 4 + 3] = f.w;
    }
    __syncthreads();
    __bf16* dst = Wt + ((size_t)h * 512 + e0) * 512 + d0;
#pragma unroll
    for (int j = 0; j < 4; ++j) {
      int ee = ty + j * 16;
      bf16x4 v;
#pragma unroll
      for (int x = 0; x < 4; ++x) v[x] = (__bf16)(tile[tx * 4 + x][ee] * scale);
      *(bf16x4*)&dst[(size_t)ee * 512 + tx * 4] = v;
    }
  } else {
#pragma unroll
    for (int j = 0; j < 4; ++j) {
      int dd = ty + j * 16;
      float4 f = *(const float4*)&Wo[(size_t)((d0 + dd) * 8 + h) * 512 + e0 + tx * 4];
      tile[dd][tx * 4 + 0] = f.x; tile[dd][tx * 4 + 1] = f.y;
      tile[dd][tx * 4 + 2] = f.z; tile[dd][tx * 4 + 3] = f.w;
    }
    __syncthreads();
#pragma unroll
    for (int j = 0; j < 4; ++j) {
      int ee = ty + j * 16;
      bf16x4 v;
#pragma unroll
      for (int x = 0; x < 4; ++x) v[x] = (__bf16)tile[tx * 4 + x][ee];
      *(bf16x4*)&Wot[(size_t)(e0 + ee) * 4096 + h * 512 + d0 + tx * 4] = v;
    }
  }
}

// ---------------------------------------------------------------------------
// fp32 -> bf16 bulk convert, 3 tensors in one launch (blockIdx.y selects).
// ---------------------------------------------------------------------------
__global__ __launch_bounds__(256) void cvt_bf16x3(const float* __restrict__ in0,
                                                  const float* __restrict__ in1,
                                                  const float* __restrict__ in2,
                                                  __bf16* __restrict__ out0,
                                                  __bf16* __restrict__ out1,
                                                  __bf16* __restrict__ out2,
                                                  int n8) {
  int i = blockIdx.x * 256 + threadIdx.x;
  if (i >= n8) return;
  const float* in = (blockIdx.y == 0) ? in0 : (blockIdx.y == 1) ? in1 : in2;
  __bf16* out = (blockIdx.y == 0) ? out0 : (blockIdx.y == 1) ? out1 : out2;
  float4 f0 = *(const float4*)&in[(size_t)i * 8];
  float4 f1 = *(const float4*)&in[(size_t)i * 8 + 4];
  bf16x8 v;
  v[0] = (__bf16)f0.x; v[1] = (__bf16)f0.y; v[2] = (__bf16)f0.z; v[3] = (__bf16)f0.w;
  v[4] = (__bf16)f1.x; v[5] = (__bf16)f1.y; v[6] = (__bf16)f1.z; v[7] = (__bf16)f1.w;
  *(bf16x8*)&out[(size_t)i * 8] = v;
}

// ---------------------------------------------------------------------------
// Shared GEMM core: 128x128 tile, BK=64, reg-staged + padded LDS (R4-proven).
// acc += A-tile * Bt-tile^T. Epilogue handled by callers.
// ---------------------------------------------------------------------------
__device__ __forceinline__ void gemm_core(const __bf16* __restrict__ A,
                                          const __bf16* __restrict__ Bt,
                                          __bf16 (*sA)[72], __bf16 (*sB)[72],
                                          floatx4 (&acc)[4][4],
                                          size_t abase, size_t bbase, int K,
                                          int wm, int wn, int lr, int lq,
                                          int srow, int scol) {
  for (int k0 = 0; k0 < K; k0 += 64) {
#pragma unroll
    for (int p = 0; p < 4; ++p) {
      int row = p * 32 + srow;
      *(bf16x8*)&sA[row][scol] = *(const bf16x8*)&A[abase + (size_t)row * K + k0 + scol];
      *(bf16x8*)&sB[row][scol] = *(const bf16x8*)&Bt[bbase + (size_t)row * K + k0 + scol];
    }
    __syncthreads();
#pragma unroll
    for (int ks = 0; ks < 2; ++ks) {
      bf16x8 af[4], bfr[4];
#pragma unroll
      for (int mt = 0; mt < 4; ++mt)
        af[mt] = *(const bf16x8*)&sA[wm + mt * 16 + lr][ks * 32 + lq * 8];
#pragma unroll
      for (int nt = 0; nt < 4; ++nt)
        bfr[nt] = *(const bf16x8*)&sB[wn + nt * 16 + lr][ks * 32 + lq * 8];
#pragma unroll
      for (int mt = 0; mt < 4; ++mt)
#pragma unroll
        for (int nt = 0; nt < 4; ++nt) acc[mt][nt] = MFMA16(af[mt], bfr[nt], acc[mt][nt]);
    }
    __syncthreads();
  }
}

// ---------------------------------------------------------------------------
// Fused projection GEMM: one launch for k,q,v. grid (32, nb*16, 3):
//   z=0: kproj = kb16*Wkt + bk   (EPI0 layout [b*8+h][m][e])
//   z=1: qproj = qb16*Wqt + bq*s (EPI0)
//   z=2: vt    = vb16*Wvt + bv   (EPI1 layout [b*8+h][e][n])
// ---------------------------------------------------------------------------
__global__ __launch_bounds__(256) void gemm_proj(const __bf16* __restrict__ kb16,
                                                 const __bf16* __restrict__ qb16,
                                                 const __bf16* __restrict__ vb16,
                                                 const __bf16* __restrict__ Wkt,
                                                 const __bf16* __restrict__ Wqt,
                                                 const __bf16* __restrict__ Wvt,
                                                 const float* __restrict__ bk,
                                                 const float* __restrict__ bq,
                                                 const float* __restrict__ bv,
                                                 __bf16* __restrict__ kproj,
                                                 __bf16* __restrict__ qproj,
                                                 __bf16* __restrict__ vt,
                                                 float qscale) {
  __shared__ __align__(16) __bf16 sA[128][72];
  __shared__ __align__(16) __bf16 sB[128][72];
  const int tid = threadIdx.x;
  const int lane = tid & 63;
  const int wave = tid >> 6;
  const int lr = lane & 15;
  const int lq = lane >> 4;
  const int wm = (wave >> 1) * 64;
  const int wn = (wave & 1) * 64;
  const int bx = blockIdx.x, by = blockIdx.y, z = blockIdx.z;
  const int srow = tid >> 3;
  const int scol = (tid & 7) << 3;
  const int K = 512;

  const __bf16* A = (z == 0) ? kb16 : (z == 1) ? qb16 : vb16;
  const __bf16* Bt = (z == 0) ? Wkt : (z == 1) ? Wqt : Wvt;
  const float* bias = (z == 0) ? bk : (z == 1) ? bq : bv;
  const float bscale = (z == 1) ? qscale : 1.0f;

  const floatx4 z4 = {0.f, 0.f, 0.f, 0.f};
  floatx4 acc[4][4];
#pragma unroll
  for (int i = 0; i < 4; ++i)
#pragma unroll
    for (int j = 0; j < 4; ++j) acc[i][j] = z4;

  gemm_core(A, Bt, sA, sB, acc, (size_t)(by * 128) * K, (size_t)(bx * 128) * K,
            K, wm, wn, lr, lq, srow, scol);

#pragma unroll
  for (int mt = 0; mt < 4; ++mt) {
#pragma unroll
    for (int nt = 0; nt < 4; ++nt) {
      int col = bx * 128 + wn + nt * 16 + lr;
      int row0 = by * 128 + wm + mt * 16 + lq * 4;
      float bcol = bias[col] * bscale;
      int h = col >> 9, e = col & 511;
      if (z < 2) {
        __bf16* dst = (z == 0) ? kproj : qproj;
#pragma unroll
        for (int r = 0; r < 4; ++r) {
          int row = row0 + r;
          int b = row >> 11, m = row & 2047;
          dst[((size_t)((b << 3) | h) * 2048 + m) * 512 + e] = (__bf16)(acc[mt][nt][r] + bcol);
        }
      } else {
        int b = row0 >> 11, n = row0 & 2047;
        bf16x4 pk;
#pragma unroll
        for (int r = 0; r < 4; ++r) pk[r] = (__bf16)(acc[mt][nt][r] + bcol);
        *(bf16x4*)&vt[((size_t)((b << 3) | h) * 512 + e) * 2048 + n] = pk;
      }
    }
  }
}

// ---------------------------------------------------------------------------
// Output GEMM: out[row][col] (fp32) = outs[M,4096] * Wot[512,4096]^T + bo
// ---------------------------------------------------------------------------
__global__ __launch_bounds__(256) void gemm_out(const __bf16* __restrict__ A,
                                                const __bf16* __restrict__ Bt,
                                                const float* __restrict__ bias,
                                                float* __restrict__ Cout, int N) {
  __shared__ __align__(16) __bf16 sA[128][72];
  __shared__ __align__(16) __bf16 sB[128][72];
  const int tid = threadIdx.x;
  const int lane = tid & 63;
  const int wave = tid >> 6;
  const int lr = lane & 15;
  const int lq = lane >> 4;
  const int wm = (wave >> 1) * 64;
  const int wn = (wave & 1) * 64;
  const int bx = blockIdx.x, by = blockIdx.y;
  const int srow = tid >> 3;
  const int scol = (tid & 7) << 3;
  const int K = 4096;

  const floatx4 z4 = {0.f, 0.f, 0.f, 0.f};
  floatx4 acc[4][4];
#pragma unroll
  for (int i = 0; i < 4; ++i)
#pragma unroll
    for (int j = 0; j < 4; ++j) acc[i][j] = z4;

  gemm_core(A, Bt, sA, sB, acc, (size_t)(by * 128) * K, (size_t)(bx * 128) * K,
            K, wm, wn, lr, lq, srow, scol);

#pragma unroll
  for (int mt = 0; mt < 4; ++mt) {
#pragma unroll
    for (int nt = 0; nt < 4; ++nt) {
      int col = bx * 128 + wn + nt * 16 + lr;
      int row0 = by * 128 + wm + mt * 16 + lq * 4;
      float bcol = bias[col];
#pragma unroll
      for (int r = 0; r < 4; ++r) {
        int row = row0 + r;
        Cout[(size_t)row * N + col] = acc[mt][nt][r] + bcol;
      }
    }
  }
}

// ---------------------------------------------------------------------------
// Flash attention, LDS-staged K + DIRECT-GLOBAL V, d-SPLIT QK + e-SLICED PV.
// R7 change: V is read exactly once per block (e-sliced PV, no reuse), so
// LDS-staging it was pure overhead (Common-mistake #7). vf loads issue at
// tile top BEFORE the K-DMA prefetch, so the compiler's pre-PV wait is
// vmcnt(4) (K-DMA stays in flight), and are consumed ~5000 cy later --
// latency covered; XCD swizzle keeps V L2-resident. Removes 64 KB/tile LDS
// traffic (-20%) and halves the B3 DMA drain.
// Everything else = R6 (verified): d-split QK w/ sx exchange, lgkm-only
// B1/B2, staging drained only at B3.
// ---------------------------------------------------------------------------
__global__ __launch_bounds__(512, 2) void attn_kernel(const __bf16* __restrict__ Qp,
                                                      const __bf16* __restrict__ Kp,
                                                      const __bf16* __restrict__ Vt,
                                                      __bf16* __restrict__ Outs) {
  __shared__ __align__(16) __bf16 kls[2][32 * 512];   // 64 KB
  __shared__ __align__(16) __bf16 pls[128 * 40];      // 10 KB
  __shared__ __align__(16) floatx4 sx[2][8][64];      // 16 KB
  __shared__ __align__(16) float l_red[128];          // row-sum exchange
  const int tid = threadIdx.x;
  const int lane = tid & 63;
  const int wave = tid >> 6;  // 0..7
  const int lr = lane & 15;
  const int lq = lane >> 4;
  const int blk = xcd_swizzle(blockIdx.x, gridDim.x);
  const int bh = blk >> 4;    // chunk-local b*8+h
  const int mblk = blk & 15;
  const int rp = (wave & 3) * 2;   // rowgroup pair base
  const int dh = wave >> 2;        // d-half of this wave
  const int fg = rp + dh;          // rowgroup this wave finalizes
  const int e0 = wave * 64;        // PV e-slice of this wave
  const int mbase = mblk * 128;
  const __bf16* Qb = Qp + (size_t)bh * (2048 * 512);
  const __bf16* Kb = Kp + (size_t)bh * (2048 * 512);
  const __bf16* Vb = Vt + (size_t)bh * (512 * 2048);

  // K staging source offsets (XOR swizzle on global side, LDS lane-linear)
  int gK[4];
#pragma unroll
  for (int i = 0; i < 4; ++i) {
    int q = i * 512 + tid;
    int rK = q >> 6;
    gK[i] = rK * 512 + ((q & 63) ^ (rK & 7)) * 8;
  }
  // V direct-load base: this wave's e-rows (per et), column block lq*8
  const __bf16* vbase[4];
#pragma unroll
  for (int et = 0; et < 4; ++et)
    vbase[et] = Vb + (size_t)(e0 + et * 16 + lr) * 2048 + lq * 8;

  // Q fragments: qf[0] = MY rowgroup (fg), qf[1] = partner's rowgroup, both
  // restricted to this wave's d-half. All register indices compile-time.
  bf16x8 qf[2][8];
#pragma unroll
  for (int ks = 0; ks < 8; ++ks) {
    qf[0][ks] = *(const bf16x8*)&Qb[(size_t)(mbase + fg * 16 + lr) * 512 +
                                    dh * 256 + ks * 32 + lq * 8];
    qf[1][ks] = *(const bf16x8*)&Qb[(size_t)(mbase + (rp + (dh ^ 1)) * 16 + lr) * 512 +
                                    dh * 256 + ks * 32 + lq * 8];
  }

  const floatx4 z4 = {0.f, 0.f, 0.f, 0.f};
  floatx4 o[8][4];  // [m-tile of 128 rows][e-tile of 64-col slice]
#pragma unroll
  for (int mt = 0; mt < 8; ++mt)
#pragma unroll
    for (int et = 0; et < 4; ++et) o[mt][et] = z4;
  float lsum[4] = {0.f, 0.f, 0.f, 0.f};

  // prologue: stage K(0) into buffer 0
#pragma unroll
  for (int i = 0; i < 4; ++i) load_lds16(Kb + gK[i], &kls[0][i * 4096 + wave * 512]);
  __syncthreads();

  for (int t = 0; t < 64; ++t) {
    const int cur = t & 1;
    // ---- V(t) direct global->reg, issued FIRST (oldest vmcnt entries)
    bf16x8 vf[4];
#pragma unroll
    for (int et = 0; et < 4; ++et) vf[et] = *(const bf16x8*)(vbase[et] + t * 32);
    // ---- async K staging of tile t+1 (in flight until B3)
    if (t < 63) {
      const __bf16* kg = Kb + (size_t)(t + 1) * (32 * 512);
#pragma unroll
      for (int i = 0; i < 4; ++i)
        load_lds16(kg + gK[i], &kls[cur ^ 1][i * 4096 + wave * 512]);
    }
    // ---- QK partials over this wave's d-half (static reg names)
    floatx4 sm0 = z4, sm1 = z4, sp0 = z4, sp1 = z4;
    const __bf16* kc = kls[cur];
#pragma unroll
    for (int ks = 0; ks < 8; ++ks) {
      int cidx = ((dh * 32 + ks * 4 + lq) ^ (lr & 7)) * 8;
      bf16x8 k0 = *(const bf16x8*)&kc[lr * 512 + cidx];
      bf16x8 k1 = *(const bf16x8*)&kc[(16 + lr) * 512 + cidx];
      sm0 = MFMA16(qf[0][ks], k0, sm0);
      sm1 = MFMA16(qf[0][ks], k1, sm1);
      sp0 = MFMA16(qf[1][ks], k0, sp0);
      sp1 = MFMA16(qf[1][ks], k1, sp1);
    }
    // ---- publish partner-rowgroup partials
    sx[0][wave][lane] = sp0;
    sx[1][wave][lane] = sp1;
    BAR_LGKM();  // B1: sx visible; K-DMA + vf still in flight
    // ---- finalize rowgroup fg: mine + partner's, exp, P-write
    {
      floatx4 q0 = sx[0][wave ^ 4][lane];
      floatx4 q1 = sx[1][wave ^ 4][lane];
#pragma unroll
      for (int r = 0; r < 4; ++r) {
        float p0 = __expf(sm0[r] + q0[r]);
        float p1 = __expf(sm1[r] + q1[r]);
        lsum[r] += p0 + p1;
        pls[(fg * 16 + lq * 4 + r) * 40 + lr] = (__bf16)p0;
        pls[(fg * 16 + lq * 4 + r) * 40 + 16 + lr] = (__bf16)p1;
      }
    }
    BAR_LGKM();  // B2: pls visible; K-DMA still in flight
    // ---- PV(t): e-slice x 128 rows; vf wait is vmcnt(4) (K-DMA unaffected)
    {
#pragma unroll
      for (int mt = 0; mt < 8; ++mt) {
        bf16x8 pf = *(const bf16x8*)&pls[(mt * 16 + lr) * 40 + lq * 8];
#pragma unroll
        for (int et = 0; et < 4; ++et) o[mt][et] = MFMA16(pf, vf[et], o[mt][et]);
      }
    }
    __syncthreads();  // B3: drains K-DMA vmcnt; guards kls/pls/sx reuse
  }

  // row-sum reduce (across lr) and exchange via LDS (O rows span all waves)
#pragma unroll
  for (int r = 0; r < 4; ++r) {
    float s = lsum[r];
    s += __shfl_xor(s, 1);
    s += __shfl_xor(s, 2);
    s += __shfl_xor(s, 4);
    s += __shfl_xor(s, 8);
    lsum[r] = s;
  }
  if (lr == 0) {
#pragma unroll
    for (int r = 0; r < 4; ++r) l_red[fg * 16 + lq * 4 + r] = lsum[r];
  }
  __syncthreads();

  int b = bh >> 3, h = bh & 7;
#pragma unroll
  for (int mt = 0; mt < 8; ++mt) {
    float4 lv = *(const float4*)&l_red[mt * 16 + lq * 4];
    float invr[4] = {1.0f / lv.x, 1.0f / lv.y, 1.0f / lv.z, 1.0f / lv.w};
    size_t rowbase = ((size_t)b * 2048 + mbase + mt * 16 + lq * 4) * 4096 + h * 512 + e0;
#pragma unroll
    for (int et = 0; et < 4; ++et)
#pragma unroll
      for (int r = 0; r < 4; ++r)
        Outs[rowbase + (size_t)r * 4096 + et * 16 + lr] = (__bf16)(o[mt][et][r] * invr[r]);
  }
}

// ---------------------------------------------------------------------------
extern "C" void kernel_launch(void* const* d_in, const int* in_sizes, int n_in,
                              void* d_out, int out_size, void* d_ws, size_t ws_size,
                              hipStream_t stream) {
  (void)in_sizes; (void)n_in; (void)out_size;
  const float* kin = (const float*)d_in[0];
  const float* vin = (const float*)d_in[1];
  const float* qin = (const float*)d_in[2];
  const float* Wk  = (const float*)d_in[3];
  const float* bk  = (const float*)d_in[4];
  const float* Wv  = (const float*)d_in[5];
  const float* bv  = (const float*)d_in[6];
  const float* Wq  = (const float*)d_in[7];
  const float* bq  = (const float*)d_in[8];
  const float* Wo  = (const float*)d_in[9];
  const float* bo  = (const float*)d_in[10];
  float* out = (float*)d_out;
  char* ws = (char*)d_ws;

  const float scale = 0.044194173824159216f;  // 1/sqrt(512), folded into Wq/bq

  const size_t SZ_W = (size_t)4096 * 512 * 2;
  const size_t SZ_B = (size_t)8 * 2048 * 512 * 2;
  const size_t FIXED = 4 * SZ_W;

  int nb = 1;
  if (ws_size >= FIXED + 8 * 4 * SZ_B) nb = 8;
  else if (ws_size >= FIXED + 4 * 4 * SZ_B) nb = 4;
  else if (ws_size >= FIXED + 2 * 4 * SZ_B) nb = 2;

  __bf16* Wkt = (__bf16*)(ws);
  __bf16* Wvt = (__bf16*)(ws + SZ_W);
  __bf16* Wqt = (__bf16*)(ws + 2 * SZ_W);
  __bf16* Wot = (__bf16*)(ws + 3 * SZ_W);
  char* chunkbase = ws + FIXED;
  __bf16* kproj = (__bf16*)(chunkbase);
  __bf16* qproj = (__bf16*)(chunkbase + (size_t)nb * SZ_B);
  __bf16* vt    = (__bf16*)(chunkbase + (size_t)nb * 2 * SZ_B);
  __bf16* outs  = (__bf16*)(chunkbase + (size_t)nb * 3 * SZ_B);

  wt_all<<<dim3(8, 8, 32), dim3(256), 0, stream>>>(Wk, Wv, Wq, Wo, Wkt, Wvt, Wqt, Wot, scale);

  for (int b0 = 0; b0 < 8; b0 += nb) {
    const float* kc = kin + (size_t)b0 * 2048 * 512;
    const float* vc = vin + (size_t)b0 * 2048 * 512;
    const float* qc = qin + (size_t)b0 * 2048 * 512;
    // pre-convert chunk inputs to bf16 (bit-identical RNE cast) into the
    // currently-unused 'outs' region (consumed by proj GEMM before attn
    // overwrites outs). One fused launch for k,q,v.
    const size_t chunk_els = (size_t)nb * 2048 * 512;
    __bf16* kb16 = outs;
    __bf16* qb16 = outs + chunk_els;
    __bf16* vb16 = outs + 2 * chunk_els;
    int n8 = (int)(chunk_els / 8);
    int cvgrid = (n8 + 255) / 256;
    cvt_bf16x3<<<dim3(cvgrid, 3), dim3(256), 0, stream>>>(kc, qc, vc, kb16, qb16, vb16, n8);
    gemm_proj<<<dim3(32, nb * 16, 3), dim3(256), 0, stream>>>(
        kb16, qb16, vb16, Wkt, Wqt, Wvt, bk, bq, bv, kproj, qproj, vt, scale);
    attn_kernel<<<dim3(nb * 128), dim3(512), 0, stream>>>(qproj, kproj, vt, outs);
    gemm_out<<<dim3(4, nb * 16), dim3(256), 0, stream>>>(
        outs, Wot, bo, out + (size_t)b0 * 2048 * 512, 512);
  }
}